// Round 6
// baseline (248.410 us; speedup 1.0000x reference)
//
#include <hip/hip_runtime.h>

// CNN self-attention: B=4, C=256, H=W=64 -> N=4096.
// Round 6: chunk-software-pipelined flash (sA/sB ping-pong): QK(i+1) MFMA
//          overlaps softmax(i) VALU in the same wave; K prefetch at step top,
//          V prefetch after tail barrier; one counted vmcnt(4)/step.
//          exp2 domain (Q pre-scaled by log2e), defer-rescale THR=12.
// Workspace: Qh,Kh,Vt f16 (24MB) + Op f16 (32MB) + stats (512KB) + Wh (384KB).

typedef _Float16 f16;
typedef f16 f16x4 __attribute__((ext_vector_type(4)));
typedef f16 f16x8 __attribute__((ext_vector_type(8)));
typedef float f32x16 __attribute__((ext_vector_type(16)));

#define NB 4
#define NC 256
#define NN 4096
#define KVSPLIT 4
#define KRANGE (NN / KVSPLIT)   // 1024 keys per split
#define NCHUNK (KRANGE / 32)    // 32 chunks of 32 keys

typedef const __attribute__((address_space(1))) void* gas_t;
typedef __attribute__((address_space(3))) void* las_t;

__device__ __forceinline__ void load_lds16(const void* g, void* l) {
    // async global->LDS DMA: LDS dest = uniform base + lane*16 (linear)
    __builtin_amdgcn_global_load_lds((gas_t)g, (las_t)l, 16, 0, 0);
}

// ---------------- Kernel 0: W fp32 -> f16 ----------------
__global__ __launch_bounds__(256) void wcvt_kernel(
    const float* __restrict__ Wq, const float* __restrict__ Wk,
    const float* __restrict__ Wv, f16* __restrict__ Wh)
{
    const int idx = blockIdx.x * 256 + threadIdx.x;   // grid = 768 blocks
    const float* s = (idx < 65536) ? Wq : (idx < 131072 ? Wk : Wv);
    Wh[idx] = (f16)s[idx & 65535];
}

// ---------------- Kernel 1: QKV projection via MFMA ----------------
// (validated rounds 2-5; change: Q scaled by log2(e) for exp2-domain softmax)
__global__ __launch_bounds__(256) void qkv_mfma_kernel(
    const float* __restrict__ x, const f16* __restrict__ Wh,
    const float* __restrict__ bq, const float* __restrict__ bk, const float* __restrict__ bv,
    f16* __restrict__ Qh, f16* __restrict__ Kh, f16* __restrict__ Vt)
{
    const int b  = blockIdx.y;
    const int n0 = blockIdx.x * 64;
    const int t  = threadIdx.x;
    const int wv = t >> 6, l = t & 63, ln = l & 31, g = l >> 5;

    __shared__ char xs[64 * 512];   // x^T tile [n][ci], swizzled granules
    __shared__ char st[32768];      // output staging

    {
        const int ci0 = t >> 4;
        const int nq  = (t & 15) * 4;
        for (int it = 0; it < 16; ++it) {
            const int ci = it * 16 + ci0;
            float v4[4];
            *(float4*)v4 = *(const float4*)(x + ((size_t)b * NC + ci) * NN + n0 + nq);
            const int gr = ci >> 3, lo = (ci & 7) * 2;
            #pragma unroll
            for (int j = 0; j < 4; ++j) {
                const int n = nq + j;
                *(f16*)(xs + n * 512 + ((gr ^ (n & 7)) * 16 + lo)) = (f16)v4[j];
            }
        }
    }
    __syncthreads();

    const int c0 = wv * 64;
    for (int m = 0; m < 3; ++m) {
        const f16*  W    = Wh + m * (NC * NC);
        const float* bias = (m == 0) ? bq : (m == 1 ? bk : bv);
        const float qs   = (m == 0) ? 1.44269504f : 1.0f;

        f32x16 acc[2][2];
        #pragma unroll
        for (int i = 0; i < 2; ++i)
            #pragma unroll
            for (int j = 0; j < 2; ++j)
                #pragma unroll
                for (int r = 0; r < 16; ++r) acc[i][j][r] = 0.0f;

        #pragma unroll
        for (int cs = 0; cs < 16; ++cs) {
            f16x8 a0 = *(const f16x8*)(W + (size_t)(c0 + ln) * NC + cs * 16 + 8 * g);
            f16x8 a1 = *(const f16x8*)(W + (size_t)(c0 + 32 + ln) * NC + cs * 16 + 8 * g);
            const int xb = (cs * 32 + g * 16) ^ ((ln & 7) << 4);
            f16x8 b0 = *(const f16x8*)(xs + ln * 512 + xb);
            f16x8 b1 = *(const f16x8*)(xs + (32 + ln) * 512 + xb);
            acc[0][0] = __builtin_amdgcn_mfma_f32_32x32x16_f16(a0, b0, acc[0][0], 0, 0, 0);
            acc[0][1] = __builtin_amdgcn_mfma_f32_32x32x16_f16(a0, b1, acc[0][1], 0, 0, 0);
            acc[1][0] = __builtin_amdgcn_mfma_f32_32x32x16_f16(a1, b0, acc[1][0], 0, 0, 0);
            acc[1][1] = __builtin_amdgcn_mfma_f32_32x32x16_f16(a1, b1, acc[1][1], 0, 0, 0);
        }

        __syncthreads();
        if (m < 2) {
            #pragma unroll
            for (int ct = 0; ct < 2; ++ct)
                #pragma unroll
                for (int nt = 0; nt < 2; ++nt)
                    #pragma unroll
                    for (int q = 0; q < 4; ++q) {
                        const int cb = c0 + ct * 32 + 8 * q + 4 * g;
                        f16x4 pk;
                        #pragma unroll
                        for (int j = 0; j < 4; ++j)
                            pk[j] = (f16)((acc[ct][nt][q * 4 + j] + bias[cb + j]) * qs);
                        const int n  = nt * 32 + ln;
                        const int g8 = cb >> 3;
                        *(f16x4*)(st + n * 512 + ((g8 ^ (n & 7)) * 16 + (cb & 7) * 2)) = pk;
                    }
            __syncthreads();
            f16* dst = (m == 0) ? Qh : Kh;
            const int gi  = t & 31;
            const int nb8 = (t >> 5) * 8;
            #pragma unroll
            for (int k = 0; k < 8; ++k) {
                const int n = nb8 + k;
                const uint4 d = *(const uint4*)(st + n * 512 + ((gi ^ (n & 7)) << 4));
                *(uint4*)(dst + ((size_t)b * NN + n0 + n) * NC + gi * 8) = d;
            }
        } else {
            #pragma unroll
            for (int ct = 0; ct < 2; ++ct)
                #pragma unroll
                for (int nt = 0; nt < 2; ++nt) {
                    const int n  = nt * 32 + ln;
                    const int pn = (n & ~15) | (n & 3) | ((n & 8) >> 1) | ((n & 4) << 1);
                    #pragma unroll
                    for (int r = 0; r < 16; ++r) {
                        const int c = c0 + ct * 32 + (r & 3) + 8 * (r >> 2) + 4 * g;
                        *(f16*)(st + c * 128 + ((pn * 2) ^ ((c & 7) << 4))) =
                            (f16)(acc[ct][nt][r] + bias[c]);
                    }
                }
            __syncthreads();
            #pragma unroll
            for (int ci = 0; ci < 8; ++ci) {
                const int c = ci * 32 + (t >> 3);
                const int s = t & 7;
                const uint4 d = *(const uint4*)(st + c * 128 + ((s ^ (c & 7)) << 4));
                *(uint4*)(Vt + ((size_t)b * NC + c) * NN + n0 + s * 8) = d;
            }
        }
    }
}

// ---------------- Kernel 2: MFMA flash attention (chunk-pipelined) ----------------
// 512 blocks x 256 thr = 2 blocks/CU. Step I: vmcnt(4)+bar -> K-DMA(I+2) ->
// QK(I+1) [MFMA, sB] || softmax(I) [VALU, sA] -> PV(I) -> bar -> V-DMA(I+2).
__global__ __launch_bounds__(256, 2) void flash_mfma_kernel(
    const f16* __restrict__ Qh, const f16* __restrict__ Kh, const f16* __restrict__ Vt,
    f16* __restrict__ Op, float* __restrict__ Mst, float* __restrict__ Lst)
{
    const int t  = threadIdx.x;
    const int wv = t >> 6;         // 0..3
    const int l  = t & 63;
    const int ln = l & 31;
    const int g  = l >> 5;

    // XCD swizzle: 2 (b,split) KV streams per XCD, 32 q-tile blocks per stream.
    const int flat  = blockIdx.x;        // 0..511
    const int xcd   = flat & 7;
    const int idx   = flat >> 3;         // 0..63
    const int bs    = xcd * 2 + (idx & 1);   // 0..15
    const int qt    = idx >> 1;          // 0..31
    const int b     = bs >> 2;
    const int split = bs & 3;
    const int qrow  = qt * 128 + wv * 32 + ln;

    __shared__ char ldsK[2 * 16384];   // [buf][32 key-rows x 512B], ^(row&15)
    __shared__ char ldsV[2 * 16384];   // [buf][64 rows x 256B] 4ch/row, ^(R&3)

    // ---- Q fragments (register-resident) ----
    f16x8 qf[16];
    {
        const f16* Qb = Qh + ((size_t)b * NN + qrow) * NC;
        #pragma unroll
        for (int cs = 0; cs < 16; ++cs)
            qf[cs] = *(const f16x8*)(Qb + cs * 16 + 8 * g);
    }

    f32x16 o[8];
    #pragma unroll
    for (int ct = 0; ct < 8; ++ct)
        #pragma unroll
        for (int r = 0; r < 16; ++r) o[ct][r] = 0.0f;

    float mrun = -1e30f, lrun = 0.0f;
    f16x8 pf[2];
    const int key_base = split * KRANGE;
    const f16* KhB = Kh + (size_t)b * NN * NC;
    const f16* VtB = Vt + (size_t)b * NC * NN;

#define KDMA(CH, BUF) do {                                                           \
        const int key0_ = key_base + (CH) * 32;                                      \
        _Pragma("unroll")                                                            \
        for (int j = 0; j < 4; ++j) {                                                \
            const int r2  = wv * 4 + j;                                              \
            const int row = r2 * 2 + (l >> 5);                                       \
            const int u   = (l & 31) ^ (row & 15);                                   \
            load_lds16(KhB + (size_t)(key0_ + row) * NC + u * 8,                     \
                       ldsK + (BUF) * 16384 + r2 * 1024);                            \
        }                                                                            \
    } while (0)

#define VDMA(CH, BUF) do {                                                           \
        const int key0_ = key_base + (CH) * 32;                                      \
        _Pragma("unroll")                                                            \
        for (int j = 0; j < 4; ++j) {                                                \
            const int i  = wv * 4 + j;                                               \
            const int R  = i * 4 + (l >> 4);                                         \
            const int c  = R * 4 + ((l & 15) >> 2);                                  \
            const int kg = (l & 3) ^ (R & 3);                                        \
            load_lds16(VtB + (size_t)c * NN + key0_ + kg * 8,                        \
                       ldsV + (BUF) * 16384 + i * 1024);                             \
        }                                                                            \
    } while (0)

    // QK: S^T = K . Q^T for one 32-key chunk (no setprio: let softmax interleave)
#define QKC(BUF, SACC) do {                                                          \
        _Pragma("unroll")                                                            \
        for (int r = 0; r < 16; ++r) SACC[r] = 0.0f;                                 \
        const char* K0_ = ldsK + (BUF) * 16384;                                      \
        _Pragma("unroll")                                                            \
        for (int cs = 0; cs < 16; ++cs) {                                            \
            const int col = ((cs * 2 + g) ^ (ln & 15)) * 16;                         \
            f16x8 a0 = *(const f16x8*)(K0_ + ln * 512 + col);                        \
            SACC = __builtin_amdgcn_mfma_f32_32x32x16_f16(a0, qf[cs], SACC, 0, 0, 0);\
        }                                                                            \
    } while (0)

    // online softmax in exp2 domain, defer-rescale THR=12 (p <= 2^12, f16-safe)
#define SM(SP) do {                                                                  \
        float mt = SP[0];                                                            \
        _Pragma("unroll")                                                            \
        for (int r = 1; r < 16; ++r) mt = fmaxf(mt, SP[r]);                          \
        mt = fmaxf(mt, __shfl_xor(mt, 32));                                          \
        if (!__all(mt <= mrun + 12.0f)) {                                            \
            const float mnew  = fmaxf(mrun, mt);                                     \
            const float alpha = exp2f(mrun - mnew);                                  \
            _Pragma("unroll")                                                        \
            for (int ct = 0; ct < 8; ++ct)                                           \
                _Pragma("unroll")                                                    \
                for (int r = 0; r < 16; ++r) o[ct][r] *= alpha;                      \
            lrun *= alpha;                                                           \
            mrun  = mnew;                                                            \
        }                                                                            \
        float ps = 0.0f;                                                             \
        _Pragma("unroll")                                                            \
        for (int r = 0; r < 16; ++r) {                                               \
            const float e0 = exp2f(SP[r] - mrun);                                    \
            ps += e0;                                                                \
            pf[r >> 3][r & 7] = (f16)e0;                                             \
        }                                                                            \
        ps += __shfl_xor(ps, 32);                                                    \
        lrun += ps;                                                                  \
    } while (0)

#define PVC(BUF) do {                                                                \
        const char* V0_ = ldsV + (BUF) * 16384;                                      \
        __builtin_amdgcn_s_setprio(1);                                               \
        _Pragma("unroll")                                                            \
        for (int ct = 0; ct < 8; ++ct) {                                             \
            const int c    = ct * 32 + ln;                                           \
            const int base = (c >> 2) * 256 + (c & 3) * 64;                          \
            const int rsw  = (c >> 2) & 3;                                           \
            _Pragma("unroll")                                                        \
            for (int s = 0; s < 2; ++s) {                                            \
                f16x8 va = *(const f16x8*)(V0_ + base + (((s * 2 + g) ^ rsw) * 16)); \
                o[ct] = __builtin_amdgcn_mfma_f32_32x32x16_f16(va, pf[s], o[ct], 0, 0, 0); \
            }                                                                        \
        }                                                                            \
        __builtin_amdgcn_s_setprio(0);                                               \
    } while (0)

    // Step I: softmax(I) from SP while QK(I+1) fills SC; PV(I); prefetch I+2.
#define STEP(SP, SC, BI, CH, PREF, DOQK, VM4) do {                                   \
        if (VM4) asm volatile("s_waitcnt vmcnt(4)" ::: "memory");                    \
        else     asm volatile("s_waitcnt vmcnt(0)" ::: "memory");                    \
        __builtin_amdgcn_s_barrier();                                                \
        if (PREF) KDMA((CH) + 2, BI);                                                \
        if (DOQK) QKC((BI) ^ 1, SC);                                                 \
        SM(SP);                                                                      \
        PVC(BI);                                                                     \
        __builtin_amdgcn_s_barrier();                                                \
        if (PREF) VDMA((CH) + 2, BI);                                                \
    } while (0)

    f32x16 sA, sB;

    // ---- prologue: K0,V0,K1 in flight; QK(0); V1 issued ----
    KDMA(0, 0);
    VDMA(0, 0);
    KDMA(1, 1);
    asm volatile("s_waitcnt vmcnt(8)" ::: "memory");   // K0 landed
    __builtin_amdgcn_s_barrier();
    QKC(0, sA);
    VDMA(1, 1);

    for (int it = 0; it < NCHUNK - 2; it += 2) {
        STEP(sA, sB, 0, it,     1, 1, 1);
        STEP(sB, sA, 1, it + 1, 1, 1, 1);
    }
    STEP(sA, sB, 0, NCHUNK - 2, 0, 1, 1);   // chunk 30 (+ QK(31))
    STEP(sB, sA, 1, NCHUNK - 1, 0, 0, 0);   // chunk 31 (drain)

#undef STEP
#undef PVC
#undef SM
#undef QKC
#undef VDMA
#undef KDMA

    // ---- epilogue: normalized partial (f16) + stats (log2-domain m) ----
    const float invl = 1.0f / lrun;
    #pragma unroll
    for (int ct = 0; ct < 8; ++ct)
        #pragma unroll
        for (int r = 0; r < 16; ++r) {
            const int c = ct * 32 + (r & 3) + 8 * (r >> 2) + 4 * g;
            Op[((size_t)(split * NB + b) * NC + c) * NN + qrow] = (f16)(o[ct][r] * invl);
        }
    if (g == 0) {
        Mst[(split * NB + b) * NN + qrow] = mrun;
        Lst[(split * NB + b) * NN + qrow] = lrun;
    }
}

// ---------------- Kernel 3: combine kv-split partials ----------------
__global__ __launch_bounds__(256) void combine_kernel(
    const f16* __restrict__ Op, const float* __restrict__ Mst, const float* __restrict__ Lst,
    float* __restrict__ out)
{
    const int t = threadIdx.x;
    const int b = blockIdx.y;
    const int n = blockIdx.x * 64 + (t & 63);

    float w[KVSPLIT];
    float mm = -1e30f;
    #pragma unroll
    for (int s = 0; s < KVSPLIT; ++s) {
        w[s] = Mst[(s * NB + b) * NN + n];
        mm = fmaxf(mm, w[s]);
    }
    float tot = 0.0f;
    #pragma unroll
    for (int s = 0; s < KVSPLIT; ++s) {
        w[s] = exp2f(w[s] - mm) * Lst[(s * NB + b) * NN + n];
        tot += w[s];
    }
    const float inv = 1.0f / tot;
    #pragma unroll
    for (int s = 0; s < KVSPLIT; ++s) w[s] *= inv;

    for (int c = (t >> 6); c < NC; c += 4) {
        float acc = 0.0f;
        #pragma unroll
        for (int s = 0; s < KVSPLIT; ++s)
            acc += w[s] * (float)Op[((size_t)(s * NB + b) * NC + c) * NN + n];
        out[((size_t)b * NC + c) * NN + n] = acc;
    }
}

extern "C" void kernel_launch(void* const* d_in, const int* in_sizes, int n_in,
                              void* d_out, int out_size, void* d_ws, size_t ws_size,
                              hipStream_t stream)
{
    const float* x  = (const float*)d_in[0];
    const float* Wq = (const float*)d_in[1];
    const float* Wk = (const float*)d_in[2];
    const float* Wv = (const float*)d_in[3];
    const float* bq = (const float*)d_in[4];
    const float* bk = (const float*)d_in[5];
    const float* bv = (const float*)d_in[6];
    float* out = (float*)d_out;

    // Workspace layout (~57 MB)
    f16* Qh = (f16*)d_ws;                                       // 8 MB
    f16* Kh = Qh + (size_t)NB * NN * NC;                        // 8 MB
    f16* Vt = Kh + (size_t)NB * NN * NC;                        // 8 MB
    f16* Op = Vt + (size_t)NB * NN * NC;                        // 32 MB
    float* Mst = (float*)(Op + (size_t)KVSPLIT * NB * NC * NN); // 256 KB
    float* Lst = Mst + (size_t)KVSPLIT * NB * NN;               // 256 KB
    f16*  Wh  = (f16*)(Lst + (size_t)KVSPLIT * NB * NN);        // 384 KB

    wcvt_kernel<<<768, 256, 0, stream>>>(Wq, Wk, Wv, Wh);
    qkv_mfma_kernel<<<dim3(NN / 64, NB), 256, 0, stream>>>(
        x, Wh, bq, bk, bv, Qh, Kh, Vt);
    flash_mfma_kernel<<<512, 256, 0, stream>>>(Qh, Kh, Vt, Op, Mst, Lst);
    combine_kernel<<<dim3(NN / 64, NB), 256, 0, stream>>>(Op, Mst, Lst, out);
}